// Round 12
// baseline (204.480 us; speedup 1.0000x reference)
//
#include <hip/hip_runtime.h>
#include <hip/hip_bf16.h>
#include <stdint.h>

#define BATCH 2
#define LQ 2048
#define LK 2048
#define DIM 1024
#define HEADS 8
#define DH 64
#define INNER 512  // HEADS*DH

typedef __attribute__((ext_vector_type(8))) short short8;
typedef __attribute__((ext_vector_type(4))) float f32x4;

__device__ __forceinline__ float bf2f(unsigned short u) {
    union { unsigned int i; float f; } v;
    v.i = ((unsigned int)u) << 16;
    return v.f;
}
__device__ __forceinline__ unsigned short f2bf(float f) {
    __hip_bfloat16 h = __float2bfloat16(f);
    return *reinterpret_cast<unsigned short*>(&h);
}
// packed 2x f32 -> bf16 (1 VALU op on gfx950), fallback to scalar RNE
__device__ __forceinline__ unsigned int f2bf2(float a, float b) {
#if __has_builtin(__builtin_amdgcn_cvt_pk_bf16_f32)
    typedef __attribute__((ext_vector_type(2))) __bf16 bf16x2;
    union { bf16x2 v; unsigned int u; } cv;
    cv.v = __builtin_amdgcn_cvt_pk_bf16_f32(a, b);
    return cv.u;
#else
    return (unsigned int)f2bf(a) | ((unsigned int)f2bf(b) << 16);
#endif
}
__device__ __forceinline__ void stc(unsigned short* C, size_t i, float v) { C[i] = f2bf(v); }
__device__ __forceinline__ void stc(float* C, size_t i, float v) { C[i] = v; }

// Direct global->LDS DMA, 16B/lane. LDS dest = wave-uniform base + lane*16.
typedef __attribute__((address_space(1))) const unsigned int gu32;
typedef __attribute__((address_space(3))) unsigned int lu32;
__device__ __forceinline__ void gload16(const void* g, void* l) {
    __builtin_amdgcn_global_load_lds((gu32*)g, (lu32*)l, 16, 0, 0);
}

// ---------------------------------------------------------------------------
// prep: fp32->bf16 copies (y=0..5) + mask bit-pack (y=6) in ONE launch so the
// latency-bound ballot job co-schedules with the BW-bound copies.
// ---------------------------------------------------------------------------
__global__ __launch_bounds__(256) void prep(
    const float* __restrict__ x,  const float* __restrict__ y,
    const float* __restrict__ wq, const float* __restrict__ wk,
    const float* __restrict__ wv, const float* __restrict__ wo,
    const float* __restrict__ mask,
    unsigned short* __restrict__ xb,  unsigned short* __restrict__ yb,
    unsigned short* __restrict__ wqb, unsigned short* __restrict__ wkb,
    unsigned short* __restrict__ wvb, unsigned short* __restrict__ wob,
    unsigned long long* __restrict__ mbits)
{
    if (blockIdx.y == 6) {
        // task = (row, 4-word chunk group): 4096 x 8 independent wave-tasks
        const int wid = blockIdx.x * 4 + (threadIdx.x >> 6);   // 4096 waves
        const int lane = threadIdx.x & 63;
        for (int task = wid; task < BATCH * LQ * 8; task += 4096) {
            int row = task >> 3, g = task & 7;
            const float* mp = mask + (size_t)row * LK + g * 256;
            unsigned long long* ob = mbits + (size_t)row * (LK / 64) + g * 4;
            float v0 = mp[0 * 64 + lane];
            float v1 = mp[1 * 64 + lane];
            float v2 = mp[2 * 64 + lane];
            float v3 = mp[3 * 64 + lane];
            unsigned long long b0 = __ballot(v0 > 0.5f);
            unsigned long long b1 = __ballot(v1 > 0.5f);
            unsigned long long b2 = __ballot(v2 > 0.5f);
            unsigned long long b3 = __ballot(v3 > 0.5f);
            if (lane == 0) { ob[0] = b0; ob[1] = b1; ob[2] = b2; ob[3] = b3; }
        }
        return;
    }
    const float* src; unsigned short* dst; int n4;
    switch (blockIdx.y) {
        case 0: src = x;  dst = xb;  n4 = (BATCH * LQ * DIM) / 4; break;
        case 1: src = y;  dst = yb;  n4 = (BATCH * LK * DIM) / 4; break;
        case 2: src = wq; dst = wqb; n4 = (INNER * DIM) / 4; break;
        case 3: src = wk; dst = wkb; n4 = (INNER * DIM) / 4; break;
        case 4: src = wv; dst = wvb; n4 = (INNER * DIM) / 4; break;
        default: src = wo; dst = wob; n4 = (INNER * DIM) / 4; break;
    }
    const int stride = gridDim.x * 256;
    for (int i = blockIdx.x * 256 + threadIdx.x; i < n4; i += stride) {
        float4 f = ((const float4*)src)[i];
        ushort4 u;
        unsigned int lo = f2bf2(f.x, f.y), hi = f2bf2(f.z, f.w);
        u.x = lo & 0xffff; u.y = lo >> 16; u.z = hi & 0xffff; u.w = hi >> 16;
        ((ushort4*)dst)[i] = u;
    }
}

// ---------------------------------------------------------------------------
// C = scale * (A[M,K] @ W[N,K]^T), bf16 in, fp32 accum. Tile = (IM*32) x
// (JN*32), BK=64, 4 waves. Swizzled global_load_lds staging (conflict-free
// b128 reads), double-buffered, one barrier/K-tile.
// EPI=0: row-major C. EPI=1: V-transpose epilogue into vt[b][h][d][key].
// ---------------------------------------------------------------------------
template <int IM, int JN, typename TC, int EPI>
__device__ __forceinline__ void gemm_body(
    const unsigned short* __restrict__ A,
    const unsigned short* __restrict__ W,
    TC* __restrict__ C,
    int K, int N, float scale,
    unsigned short* As, unsigned short* Bs)
{
    constexpr int BM = IM * 32;
    constexpr int BN = JN * 32;
    constexpr int ACH = BM * 8;
    constexpr int BCH = BN * 8;
    constexpr int AUS = BM * 64;
    constexpr int BUS = BN * 64;

    const int tid = threadIdx.x;
    const int m0 = blockIdx.x * BM;
    const int n0 = blockIdx.y * BN;
    const int w = tid >> 6, lane = tid & 63;
    const int q4 = lane >> 4, l16 = lane & 15;
    const int wm = (w >> 1) * (IM * 16), wn = (w & 1) * (JN * 16);
    const int sw = l16 & 7;

    f32x4 acc[IM][JN] = {};

#pragma unroll
    for (int i = 0; i < ACH / 256; ++i) {
        int s = tid + i * 256;
        int r = s >> 3, ch = (s & 7) ^ (r & 7);
        gload16(A + (size_t)(m0 + r) * K + ch * 8, As + (size_t)s * 8);
    }
#pragma unroll
    for (int i = 0; i < BCH / 256; ++i) {
        int s = tid + i * 256;
        int r = s >> 3, ch = (s & 7) ^ (r & 7);
        gload16(W + (size_t)(n0 + r) * K + ch * 8, Bs + (size_t)s * 8);
    }
    __syncthreads();

    const int nt = K / 64;
    for (int t = 0; t < nt; ++t) {
        const int curA = (t & 1) * AUS;
        const int curB = (t & 1) * BUS;
        if (t + 1 < nt) {
            int kk = (t + 1) * 64;
            const int nxtA = AUS - curA, nxtB = BUS - curB;
#pragma unroll
            for (int i = 0; i < ACH / 256; ++i) {
                int s = tid + i * 256;
                int r = s >> 3, ch = (s & 7) ^ (r & 7);
                gload16(A + (size_t)(m0 + r) * K + kk + ch * 8, As + nxtA + (size_t)s * 8);
            }
#pragma unroll
            for (int i = 0; i < BCH / 256; ++i) {
                int s = tid + i * 256;
                int r = s >> 3, ch = (s & 7) ^ (r & 7);
                gload16(W + (size_t)(n0 + r) * K + kk + ch * 8, Bs + nxtB + (size_t)s * 8);
            }
        }

#pragma unroll
        for (int ks = 0; ks < 2; ++ks) {
            const int kq = ((ks * 4 + q4) ^ sw) * 8;
            short8 a[IM], b[JN];
#pragma unroll
            for (int i = 0; i < IM; ++i)
                a[i] = *(const short8*)(As + curA + (wm + i * 16 + l16) * 64 + kq);
#pragma unroll
            for (int j = 0; j < JN; ++j)
                b[j] = *(const short8*)(Bs + curB + (wn + j * 16 + l16) * 64 + kq);
#pragma unroll
            for (int i = 0; i < IM; ++i)
#pragma unroll
                for (int j = 0; j < JN; ++j)
                    acc[i][j] = __builtin_amdgcn_mfma_f32_16x16x32_bf16(
                        a[i], b[j], acc[i][j], 0, 0, 0);
        }
        __syncthreads();
    }

    if (EPI == 0) {
        // C/D layout: col = lane&15, row = quad*4 + reg  [m89-verified]
#pragma unroll
        for (int i = 0; i < IM; ++i)
#pragma unroll
            for (int j = 0; j < JN; ++j)
#pragma unroll
                for (int r = 0; r < 4; ++r) {
                    int row = m0 + wm + i * 16 + q4 * 4 + r;
                    int col = n0 + wn + j * 16 + l16;
                    stc(C, (size_t)row * N + col, acc[i][j][r] * scale);
                }
    } else {
        // V-transpose epilogue into vt[((b*H+h)*DH+d)*LK + key].
        constexpr int KW = IM * 16;
        constexpr int DW = JN * 16;
        constexpr int TPS = KW + 8;
        unsigned short* TP = As + w * (DW * TPS);
#pragma unroll
        for (int i = 0; i < IM; ++i)
#pragma unroll
            for (int j = 0; j < JN; ++j) {
                unsigned int lo = f2bf2(acc[i][j][0], acc[i][j][1]);
                unsigned int hi = f2bf2(acc[i][j][2], acc[i][j][3]);
                ushort4 u;
                u.x = lo & 0xffff; u.y = lo >> 16; u.z = hi & 0xffff; u.w = hi >> 16;
                *(ushort4*)(TP + (j * 16 + l16) * TPS + i * 16 + q4 * 4) = u;
            }
        const int keyflat = m0 + wm;
        const int bb = keyflat >> 11, key0 = keyflat & (LK - 1);
        const int hh = (n0 + wn) >> 6;
        const int dlow = (n0 + wn) & 63;
        constexpr int RCH = KW / 8;
        constexpr int NCH = DW * RCH;
#pragma unroll
        for (int p = 0; p < NCH / 64; ++p) {
            int c = p * 64 + lane;
            int dl = c / RCH, kc = c % RCH;
            uint4 v = *(const uint4*)(TP + dl * TPS + kc * 8);
            *(uint4*)((unsigned short*)C +
                ((size_t)((bb * HEADS + hh) * DH + dlow + dl)) * LK + key0 + kc * 8) = v;
        }
    }
}

// q is scaled by 0.125*log2(e) so attn can use exp2 directly.
#define QSCALE 0.18033688011112042f

__global__ __launch_bounds__(256) void proj_qkv(
    const unsigned short* __restrict__ xb, const unsigned short* __restrict__ yb,
    const unsigned short* __restrict__ wqb, const unsigned short* __restrict__ wkb,
    const unsigned short* __restrict__ wvb,
    unsigned short* __restrict__ qb, unsigned short* __restrict__ kb,
    unsigned short* __restrict__ vt)
{
    __shared__ __align__(16) unsigned short As[2 * 128 * 64];
    __shared__ __align__(16) unsigned short Bs[2 * 64 * 64];
    const int z = blockIdx.z;
    const unsigned short* A = (z == 0) ? xb : yb;
    const unsigned short* W = (z == 0) ? wqb : (z == 1) ? wkb : wvb;
    if (z == 2)
        gemm_body<4, 2, unsigned short, 1>(A, W, vt, DIM, INNER, 1.0f, As, Bs);
    else
        gemm_body<4, 2, unsigned short, 0>(A, W, (z == 0) ? qb : kb, DIM, INNER,
                                           (z == 0) ? QSCALE : 1.0f, As, Bs);
}

__global__ __launch_bounds__(256) void gemm_out(
    const unsigned short* __restrict__ A,
    const unsigned short* __restrict__ W,
    float* __restrict__ C)
{
    __shared__ __align__(16) unsigned short As[2 * 128 * 64];
    __shared__ __align__(16) unsigned short Bs[2 * 64 * 64];
    gemm_body<4, 2, float, 0>(A, W, C, INNER, DIM, 1.0f, As, Bs);
}

// ---------------------------------------------------------------------------
// Flash attention (R10 skeleton): 64 q rows/block, 4 waves, shared K/V
// double-buffered via swizzled global_load_lds, ONE barrier per 64-key tile.
// P per-wave LDS round-trip (in-order DS). exp2 softmax (scale folded into
// q), bitmask, packed bf16 cvt.
// ---------------------------------------------------------------------------
#define AT_US (64 * 64)

__global__ __launch_bounds__(256) void attn_mfma(
    const unsigned short* __restrict__ Q,
    const unsigned short* __restrict__ Kb,
    const unsigned short* __restrict__ Vt,
    const unsigned long long* __restrict__ Mb,
    unsigned short* __restrict__ O)
{
    __shared__ __align__(16) unsigned short Ks[2 * AT_US];
    __shared__ __align__(16) unsigned short Vs[2 * AT_US];
    __shared__ __align__(16) unsigned short Ps[4][16 * 72];

    const int tid = threadIdx.x;
    const int q0 = blockIdx.x * 64;
    const int h = blockIdx.y, b = blockIdx.z;
    const int w = tid >> 6, lane = tid & 63;
    const int q4 = lane >> 4, l16 = lane & 15;
    const int sw = l16 & 7;

    short8 qf[2];
    {
        const unsigned short* qp =
            Q + (size_t)(b * LQ + q0 + w * 16 + l16) * INNER + h * DH + q4 * 8;
        qf[0] = *(const short8*)(qp);
        qf[1] = *(const short8*)(qp + 32);
    }

    f32x4 o[4] = {};
    float lacc[4] = {0.f, 0.f, 0.f, 0.f};

    const unsigned short* kbase = Kb + (size_t)(b * LK) * INNER + h * DH;
    const unsigned short* vbase = Vt + (size_t)((b * HEADS + h) * DH) * LK;
    const unsigned long long* mrow =
        Mb + (size_t)(b * LQ + q0 + w * 16 + q4 * 4) * (LK / 64);

    const int r0 = tid >> 3, ch0 = (tid & 7) ^ (r0 & 7);
    const int s1 = tid + 256;
    const int r1 = s1 >> 3, ch1 = (s1 & 7) ^ (r1 & 7);

    gload16(kbase + (size_t)r0 * INNER + ch0 * 8, Ks + (size_t)tid * 8);
    gload16(kbase + (size_t)r1 * INNER + ch1 * 8, Ks + (size_t)s1 * 8);
    gload16(vbase + (size_t)r0 * LK + ch0 * 8, Vs + (size_t)tid * 8);
    gload16(vbase + (size_t)r1 * LK + ch1 * 8, Vs + (size_t)s1 * 8);
    __syncthreads();

    const int NT = LK / 64;   // 32
    for (int t = 0; t < NT; ++t) {
        const int cur = (t & 1) * AT_US;
        if (t + 1 < NT) {
            const int nxt = AT_US - cur;
            int kn = (t + 1) * 64;
            gload16(kbase + (size_t)(kn + r0) * INNER + ch0 * 8, Ks + nxt + (size_t)tid * 8);
            gload16(kbase + (size_t)(kn + r1) * INNER + ch1 * 8, Ks + nxt + (size_t)s1 * 8);
            gload16(vbase + (size_t)r0 * LK + kn + ch0 * 8, Vs + nxt + (size_t)tid * 8);
            gload16(vbase + (size_t)r1 * LK + kn + ch1 * 8, Vs + nxt + (size_t)s1 * 8);
        }

        // ---- S = Q K^T (swizzled kf reads) ----
        f32x4 s[4];
#pragma unroll
        for (int j = 0; j < 4; ++j) {
            s[j] = f32x4{0.f, 0.f, 0.f, 0.f};
#pragma unroll
            for (int ks = 0; ks < 2; ++ks) {
                short8 kf = *(const short8*)(Ks + cur + (j * 16 + l16) * 64
                                             + (((ks * 4 + q4) ^ sw) * 8));
                s[j] = __builtin_amdgcn_mfma_f32_16x16x32_bf16(qf[ks], kf, s[j], 0, 0, 0);
            }
        }

        // ---- p = masked ? 0 : exp2(s)  (log2e folded into q) ----
#pragma unroll
        for (int r = 0; r < 4; ++r) {
            unsigned long long bits = mrow[(size_t)r * (LK / 64) + t];
#pragma unroll
            for (int j = 0; j < 4; ++j) {
                float e = exp2f(s[j][r]);
                float pe = ((bits >> (j * 16 + l16)) & 1ull) ? 0.f : e;
                s[j][r] = pe;
                lacc[r] += pe;
            }
        }

        // ---- P (C-layout) -> per-wave LDS (no barrier; in-order DS) ----
#pragma unroll
        for (int j = 0; j < 4; ++j) {
            unsigned int lo = f2bf2(s[j][0], s[j][1]);
            unsigned int hi = f2bf2(s[j][2], s[j][3]);
            Ps[w][(q4 * 4 + 0) * 72 + j * 16 + l16] = lo & 0xffff;
            Ps[w][(q4 * 4 + 1) * 72 + j * 16 + l16] = lo >> 16;
            Ps[w][(q4 * 4 + 2) * 72 + j * 16 + l16] = hi & 0xffff;
            Ps[w][(q4 * 4 + 3) * 72 + j * 16 + l16] = hi >> 16;
        }

        // ---- O += P V (swizzled vf reads) ----
#pragma unroll
        for (int ks = 0; ks < 2; ++ks) {
            short8 pf = *(const short8*)(&Ps[w][l16 * 72 + ks * 32 + q4 * 8]);
#pragma unroll
            for (int dd = 0; dd < 4; ++dd) {
                short8 vf = *(const short8*)(Vs + cur + (dd * 16 + l16) * 64
                                             + (((ks * 4 + q4) ^ sw) * 8));
                o[dd] = __builtin_amdgcn_mfma_f32_16x16x32_bf16(pf, vf, o[dd], 0, 0, 0);
            }
        }
        __syncthreads();
    }

    // ---- reduce l across the 16 key-lanes, then store ----
#pragma unroll
    for (int off = 1; off < 16; off <<= 1)
#pragma unroll
        for (int r = 0; r < 4; ++r)
            lacc[r] += __shfl_xor(lacc[r], off);
    float inv[4];
#pragma unroll
    for (int r = 0; r < 4; ++r) inv[r] = 1.0f / lacc[r];

#pragma unroll
    for (int dd = 0; dd < 4; ++dd)
#pragma unroll
        for (int r = 0; r < 4; ++r) {
            int qrow = b * LQ + q0 + w * 16 + q4 * 4 + r;
            int col = h * DH + dd * 16 + l16;
            O[(size_t)qrow * INNER + col] = f2bf(o[dd][r] * inv[r]);
        }
}

extern "C" void kernel_launch(void* const* d_in, const int* in_sizes, int n_in,
                              void* d_out, int out_size, void* d_ws, size_t ws_size,
                              hipStream_t stream) {
    const float* x    = (const float*)d_in[0];
    const float* y    = (const float*)d_in[1];
    const float* mask = (const float*)d_in[2];
    const float* Wq   = (const float*)d_in[3];
    const float* Wk   = (const float*)d_in[4];
    const float* Wv   = (const float*)d_in[5];
    const float* Wo   = (const float*)d_in[6];
    float* out = (float*)d_out;

    const size_t NX = (size_t)BATCH * LQ * DIM;    // 4.19M
    const size_t NS = (size_t)BATCH * LQ * INNER;  // 2.10M
    const size_t NW = (size_t)INNER * DIM;         // 0.52M
    unsigned short* xb  = (unsigned short*)d_ws;
    unsigned short* yb  = xb + NX;
    unsigned short* qb  = yb + NX;
    unsigned short* kb  = qb + NS;
    unsigned short* vt  = kb + NS;
    unsigned short* wqb = vt + NS;
    unsigned short* wkb = wqb + NW;
    unsigned short* wvb = wkb + NW;
    unsigned short* wob = wvb + NW;
    unsigned long long* mbits = (unsigned long long*)(wob + NW);
    unsigned short* ao  = xb;   // xb dead after proj
    // ws: 33.8 MB bf16 + 1 MB bits

    dim3 blk(256);
    prep<<<dim3(1024, 7), blk, 0, stream>>>(
        x, y, Wq, Wk, Wv, Wo, mask, xb, yb, wqb, wkb, wvb, wob, mbits);
    proj_qkv<<<dim3(4096 / 128, INNER / 64, 3), blk, 0, stream>>>(
        xb, yb, wqb, wkb, wvb, qb, kb, vt);
    attn_mfma<<<dim3(LQ / 64, HEADS, BATCH), blk, 0, stream>>>(
        qb, kb, vt, mbits, ao);
    gemm_out<<<dim3(4096 / 128, DIM / 64), blk, 0, stream>>>(ao, wob, out);
}

// Round 13
// 192.851 us; speedup vs baseline: 1.0603x; 1.0603x over previous
//
#include <hip/hip_runtime.h>
#include <hip/hip_bf16.h>
#include <stdint.h>

#define BATCH 2
#define LQ 2048
#define LK 2048
#define DIM 1024
#define HEADS 8
#define DH 64
#define INNER 512  // HEADS*DH

typedef __attribute__((ext_vector_type(8))) short short8;
typedef __attribute__((ext_vector_type(4))) float f32x4;

__device__ __forceinline__ float bf2f(unsigned short u) {
    union { unsigned int i; float f; } v;
    v.i = ((unsigned int)u) << 16;
    return v.f;
}
__device__ __forceinline__ unsigned short f2bf(float f) {
    __hip_bfloat16 h = __float2bfloat16(f);
    return *reinterpret_cast<unsigned short*>(&h);
}
// raw v_exp_f32 (2^x); __expf would add a *log2e mul we fold into QSCALE
__device__ __forceinline__ float fexp2(float x) {
#if __has_builtin(__builtin_amdgcn_exp2f)
    return __builtin_amdgcn_exp2f(x);
#else
    return __expf(x * 0.69314718056f);
#endif
}
__device__ __forceinline__ void stc(unsigned short* C, size_t i, float v) { C[i] = f2bf(v); }
__device__ __forceinline__ void stc(float* C, size_t i, float v) { C[i] = v; }

// Direct global->LDS DMA, 16B/lane. LDS dest = wave-uniform base + lane*16.
typedef __attribute__((address_space(1))) const unsigned int gu32;
typedef __attribute__((address_space(3))) unsigned int lu32;
__device__ __forceinline__ void gload16(const void* g, void* l) {
    __builtin_amdgcn_global_load_lds((gu32*)g, (lu32*)l, 16, 0, 0);
}

// ---------------------------------------------------------------------------
// prep: fp32->bf16 copies (y=0..5, scalar RNE cvt) + mask bit-pack (y=6),
// one launch. Mask job: 32768 independent wave-tasks, 4 loads in flight.
// ---------------------------------------------------------------------------
__global__ __launch_bounds__(256) void prep(
    const float* __restrict__ x,  const float* __restrict__ y,
    const float* __restrict__ wq, const float* __restrict__ wk,
    const float* __restrict__ wv, const float* __restrict__ wo,
    const float* __restrict__ mask,
    unsigned short* __restrict__ xb,  unsigned short* __restrict__ yb,
    unsigned short* __restrict__ wqb, unsigned short* __restrict__ wkb,
    unsigned short* __restrict__ wvb, unsigned short* __restrict__ wob,
    unsigned long long* __restrict__ mbits)
{
    if (blockIdx.y == 6) {
        const int wid = blockIdx.x * 4 + (threadIdx.x >> 6);   // 4096 waves
        const int lane = threadIdx.x & 63;
        for (int task = wid; task < BATCH * LQ * 8; task += 4096) {
            int row = task >> 3, g = task & 7;
            const float* mp = mask + (size_t)row * LK + g * 256;
            unsigned long long* ob = mbits + (size_t)row * (LK / 64) + g * 4;
            float v0 = mp[0 * 64 + lane];
            float v1 = mp[1 * 64 + lane];
            float v2 = mp[2 * 64 + lane];
            float v3 = mp[3 * 64 + lane];
            unsigned long long b0 = __ballot(v0 > 0.5f);
            unsigned long long b1 = __ballot(v1 > 0.5f);
            unsigned long long b2 = __ballot(v2 > 0.5f);
            unsigned long long b3 = __ballot(v3 > 0.5f);
            if (lane == 0) { ob[0] = b0; ob[1] = b1; ob[2] = b2; ob[3] = b3; }
        }
        return;
    }
    const float* src; unsigned short* dst; int n4;
    switch (blockIdx.y) {
        case 0: src = x;  dst = xb;  n4 = (BATCH * LQ * DIM) / 4; break;
        case 1: src = y;  dst = yb;  n4 = (BATCH * LK * DIM) / 4; break;
        case 2: src = wq; dst = wqb; n4 = (INNER * DIM) / 4; break;
        case 3: src = wk; dst = wkb; n4 = (INNER * DIM) / 4; break;
        case 4: src = wv; dst = wvb; n4 = (INNER * DIM) / 4; break;
        default: src = wo; dst = wob; n4 = (INNER * DIM) / 4; break;
    }
    const int stride = gridDim.x * 256;
    for (int i = blockIdx.x * 256 + threadIdx.x; i < n4; i += stride) {
        float4 f = ((const float4*)src)[i];
        ushort4 u;
        u.x = f2bf(f.x); u.y = f2bf(f.y); u.z = f2bf(f.z); u.w = f2bf(f.w);
        ((ushort4*)dst)[i] = u;
    }
}

// ---------------------------------------------------------------------------
// C = scale * (A[M,K] @ W[N,K]^T), bf16 in, fp32 accum. Tile = (IM*32) x
// (JN*32), BK=64, 4 waves. Swizzled global_load_lds staging (conflict-free
// b128 reads), double-buffered, one barrier/K-tile.
// EPI=0: row-major C. EPI=1: V-transpose epilogue into vt[b][h][d][key].
// ---------------------------------------------------------------------------
template <int IM, int JN, typename TC, int EPI>
__device__ __forceinline__ void gemm_body(
    const unsigned short* __restrict__ A,
    const unsigned short* __restrict__ W,
    TC* __restrict__ C,
    int K, int N, float scale,
    unsigned short* As, unsigned short* Bs)
{
    constexpr int BM = IM * 32;
    constexpr int BN = JN * 32;
    constexpr int ACH = BM * 8;
    constexpr int BCH = BN * 8;
    constexpr int AUS = BM * 64;
    constexpr int BUS = BN * 64;

    const int tid = threadIdx.x;
    const int m0 = blockIdx.x * BM;
    const int n0 = blockIdx.y * BN;
    const int w = tid >> 6, lane = tid & 63;
    const int q4 = lane >> 4, l16 = lane & 15;
    const int wm = (w >> 1) * (IM * 16), wn = (w & 1) * (JN * 16);
    const int sw = l16 & 7;

    f32x4 acc[IM][JN] = {};

#pragma unroll
    for (int i = 0; i < ACH / 256; ++i) {
        int s = tid + i * 256;
        int r = s >> 3, ch = (s & 7) ^ (r & 7);
        gload16(A + (size_t)(m0 + r) * K + ch * 8, As + (size_t)s * 8);
    }
#pragma unroll
    for (int i = 0; i < BCH / 256; ++i) {
        int s = tid + i * 256;
        int r = s >> 3, ch = (s & 7) ^ (r & 7);
        gload16(W + (size_t)(n0 + r) * K + ch * 8, Bs + (size_t)s * 8);
    }
    __syncthreads();

    const int nt = K / 64;
    for (int t = 0; t < nt; ++t) {
        const int curA = (t & 1) * AUS;
        const int curB = (t & 1) * BUS;
        if (t + 1 < nt) {
            int kk = (t + 1) * 64;
            const int nxtA = AUS - curA, nxtB = BUS - curB;
#pragma unroll
            for (int i = 0; i < ACH / 256; ++i) {
                int s = tid + i * 256;
                int r = s >> 3, ch = (s & 7) ^ (r & 7);
                gload16(A + (size_t)(m0 + r) * K + kk + ch * 8, As + nxtA + (size_t)s * 8);
            }
#pragma unroll
            for (int i = 0; i < BCH / 256; ++i) {
                int s = tid + i * 256;
                int r = s >> 3, ch = (s & 7) ^ (r & 7);
                gload16(W + (size_t)(n0 + r) * K + kk + ch * 8, Bs + nxtB + (size_t)s * 8);
            }
        }

#pragma unroll
        for (int ks = 0; ks < 2; ++ks) {
            const int kq = ((ks * 4 + q4) ^ sw) * 8;
            short8 a[IM], b[JN];
#pragma unroll
            for (int i = 0; i < IM; ++i)
                a[i] = *(const short8*)(As + curA + (wm + i * 16 + l16) * 64 + kq);
#pragma unroll
            for (int j = 0; j < JN; ++j)
                b[j] = *(const short8*)(Bs + curB + (wn + j * 16 + l16) * 64 + kq);
#pragma unroll
            for (int i = 0; i < IM; ++i)
#pragma unroll
                for (int j = 0; j < JN; ++j)
                    acc[i][j] = __builtin_amdgcn_mfma_f32_16x16x32_bf16(
                        a[i], b[j], acc[i][j], 0, 0, 0);
        }
        __syncthreads();
    }

    if (EPI == 0) {
        // C/D layout: col = lane&15, row = quad*4 + reg  [m89-verified]
#pragma unroll
        for (int i = 0; i < IM; ++i)
#pragma unroll
            for (int j = 0; j < JN; ++j)
#pragma unroll
                for (int r = 0; r < 4; ++r) {
                    int row = m0 + wm + i * 16 + q4 * 4 + r;
                    int col = n0 + wn + j * 16 + l16;
                    stc(C, (size_t)row * N + col, acc[i][j][r] * scale);
                }
    } else {
        // V-transpose epilogue into vt[((b*H+h)*DH+d)*LK + key].
        constexpr int KW = IM * 16;
        constexpr int DW = JN * 16;
        constexpr int TPS = KW + 8;
        unsigned short* TP = As + w * (DW * TPS);
#pragma unroll
        for (int i = 0; i < IM; ++i)
#pragma unroll
            for (int j = 0; j < JN; ++j) {
                ushort4 u;
                u.x = f2bf(acc[i][j][0]); u.y = f2bf(acc[i][j][1]);
                u.z = f2bf(acc[i][j][2]); u.w = f2bf(acc[i][j][3]);
                *(ushort4*)(TP + (j * 16 + l16) * TPS + i * 16 + q4 * 4) = u;
            }
        const int keyflat = m0 + wm;
        const int bb = keyflat >> 11, key0 = keyflat & (LK - 1);
        const int hh = (n0 + wn) >> 6;
        const int dlow = (n0 + wn) & 63;
        constexpr int RCH = KW / 8;
        constexpr int NCH = DW * RCH;
#pragma unroll
        for (int p = 0; p < NCH / 64; ++p) {
            int c = p * 64 + lane;
            int dl = c / RCH, kc = c % RCH;
            uint4 v = *(const uint4*)(TP + dl * TPS + kc * 8);
            *(uint4*)((unsigned short*)C +
                ((size_t)((bb * HEADS + hh) * DH + dlow + dl)) * LK + key0 + kc * 8) = v;
        }
    }
}

// q scaled by 0.125*log2(e) so attn uses raw v_exp_f32 (2^x) directly.
#define QSCALE 0.18033688011112042f

__global__ __launch_bounds__(256) void proj_qkv(
    const unsigned short* __restrict__ xb, const unsigned short* __restrict__ yb,
    const unsigned short* __restrict__ wqb, const unsigned short* __restrict__ wkb,
    const unsigned short* __restrict__ wvb,
    unsigned short* __restrict__ qb, unsigned short* __restrict__ kb,
    unsigned short* __restrict__ vt)
{
    __shared__ __align__(16) unsigned short As[2 * 128 * 64];
    __shared__ __align__(16) unsigned short Bs[2 * 64 * 64];
    const int z = blockIdx.z;
    const unsigned short* A = (z == 0) ? xb : yb;
    const unsigned short* W = (z == 0) ? wqb : (z == 1) ? wkb : wvb;
    if (z == 2)
        gemm_body<4, 2, unsigned short, 1>(A, W, vt, DIM, INNER, 1.0f, As, Bs);
    else
        gemm_body<4, 2, unsigned short, 0>(A, W, (z == 0) ? qb : kb, DIM, INNER,
                                           (z == 0) ? QSCALE : 1.0f, As, Bs);
}

__global__ __launch_bounds__(256) void gemm_out(
    const unsigned short* __restrict__ A,
    const unsigned short* __restrict__ W,
    float* __restrict__ C)
{
    __shared__ __align__(16) unsigned short As[2 * 128 * 64];
    __shared__ __align__(16) unsigned short Bs[2 * 64 * 64];
    gemm_body<4, 2, float, 0>(A, W, C, INNER, DIM, 1.0f, As, Bs);
}

// ---------------------------------------------------------------------------
// Flash attention (R11 code, proven 55.8 µs; only change: fexp2 with scale
// folded into q). 64 q rows/block, 4 waves, shared K/V double-buffered via
// swizzled global_load_lds, ONE barrier per 64-key tile. P per-wave LDS
// round-trip (in-order DS). No-max softmax + bitmask.
// ---------------------------------------------------------------------------
#define AT_US (64 * 64)

__global__ __launch_bounds__(256) void attn_mfma(
    const unsigned short* __restrict__ Q,
    const unsigned short* __restrict__ Kb,
    const unsigned short* __restrict__ Vt,
    const unsigned long long* __restrict__ Mb,
    unsigned short* __restrict__ O)
{
    __shared__ __align__(16) unsigned short Ks[2 * AT_US];
    __shared__ __align__(16) unsigned short Vs[2 * AT_US];
    __shared__ __align__(16) unsigned short Ps[4][16 * 72];

    const int tid = threadIdx.x;
    const int q0 = blockIdx.x * 64;
    const int h = blockIdx.y, b = blockIdx.z;
    const int w = tid >> 6, lane = tid & 63;
    const int q4 = lane >> 4, l16 = lane & 15;
    const int sw = l16 & 7;

    short8 qf[2];
    {
        const unsigned short* qp =
            Q + (size_t)(b * LQ + q0 + w * 16 + l16) * INNER + h * DH + q4 * 8;
        qf[0] = *(const short8*)(qp);
        qf[1] = *(const short8*)(qp + 32);
    }

    f32x4 o[4] = {};
    float lacc[4] = {0.f, 0.f, 0.f, 0.f};

    const unsigned short* kbase = Kb + (size_t)(b * LK) * INNER + h * DH;
    const unsigned short* vbase = Vt + (size_t)((b * HEADS + h) * DH) * LK;
    const unsigned long long* mrow =
        Mb + (size_t)(b * LQ + q0 + w * 16 + q4 * 4) * (LK / 64);

    const int r0 = tid >> 3, ch0 = (tid & 7) ^ (r0 & 7);
    const int s1 = tid + 256;
    const int r1 = s1 >> 3, ch1 = (s1 & 7) ^ (r1 & 7);

    gload16(kbase + (size_t)r0 * INNER + ch0 * 8, Ks + (size_t)tid * 8);
    gload16(kbase + (size_t)r1 * INNER + ch1 * 8, Ks + (size_t)s1 * 8);
    gload16(vbase + (size_t)r0 * LK + ch0 * 8, Vs + (size_t)tid * 8);
    gload16(vbase + (size_t)r1 * LK + ch1 * 8, Vs + (size_t)s1 * 8);
    __syncthreads();

    const int NT = LK / 64;   // 32
    for (int t = 0; t < NT; ++t) {
        const int cur = (t & 1) * AT_US;
        if (t + 1 < NT) {
            const int nxt = AT_US - cur;
            int kn = (t + 1) * 64;
            gload16(kbase + (size_t)(kn + r0) * INNER + ch0 * 8, Ks + nxt + (size_t)tid * 8);
            gload16(kbase + (size_t)(kn + r1) * INNER + ch1 * 8, Ks + nxt + (size_t)s1 * 8);
            gload16(vbase + (size_t)r0 * LK + kn + ch0 * 8, Vs + nxt + (size_t)tid * 8);
            gload16(vbase + (size_t)r1 * LK + kn + ch1 * 8, Vs + nxt + (size_t)s1 * 8);
        }

        // ---- S = Q K^T (swizzled kf reads) ----
        f32x4 s[4];
#pragma unroll
        for (int j = 0; j < 4; ++j) {
            s[j] = f32x4{0.f, 0.f, 0.f, 0.f};
#pragma unroll
            for (int ks = 0; ks < 2; ++ks) {
                short8 kf = *(const short8*)(Ks + cur + (j * 16 + l16) * 64
                                             + (((ks * 4 + q4) ^ sw) * 8));
                s[j] = __builtin_amdgcn_mfma_f32_16x16x32_bf16(qf[ks], kf, s[j], 0, 0, 0);
            }
        }

        // ---- p = masked ? 0 : 2^s  (log2e folded into q) ----
#pragma unroll
        for (int r = 0; r < 4; ++r) {
            unsigned long long bits = mrow[(size_t)r * (LK / 64) + t];
#pragma unroll
            for (int j = 0; j < 4; ++j) {
                float e = fexp2(s[j][r]);
                float pe = ((bits >> (j * 16 + l16)) & 1ull) ? 0.f : e;
                s[j][r] = pe;
                lacc[r] += pe;
            }
        }

        // ---- P (C-layout) -> per-wave LDS (no barrier; in-order DS) ----
#pragma unroll
        for (int j = 0; j < 4; ++j)
#pragma unroll
            for (int r = 0; r < 4; ++r)
                Ps[w][(q4 * 4 + r) * 72 + j * 16 + l16] = f2bf(s[j][r]);

        // ---- O += P V (swizzled vf reads) ----
#pragma unroll
        for (int ks = 0; ks < 2; ++ks) {
            short8 pf = *(const short8*)(&Ps[w][l16 * 72 + ks * 32 + q4 * 8]);
#pragma unroll
            for (int dd = 0; dd < 4; ++dd) {
                short8 vf = *(const short8*)(Vs + cur + (dd * 16 + l16) * 64
                                             + (((ks * 4 + q4) ^ sw) * 8));
                o[dd] = __builtin_amdgcn_mfma_f32_16x16x32_bf16(pf, vf, o[dd], 0, 0, 0);
            }
        }
        __syncthreads();
    }

    // ---- reduce l across the 16 key-lanes, then store ----
#pragma unroll
    for (int off = 1; off < 16; off <<= 1)
#pragma unroll
        for (int r = 0; r < 4; ++r)
            lacc[r] += __shfl_xor(lacc[r], off);
    float inv[4];
#pragma unroll
    for (int r = 0; r < 4; ++r) inv[r] = 1.0f / lacc[r];

#pragma unroll
    for (int dd = 0; dd < 4; ++dd)
#pragma unroll
        for (int r = 0; r < 4; ++r) {
            int qrow = b * LQ + q0 + w * 16 + q4 * 4 + r;
            int col = h * DH + dd * 16 + l16;
            O[(size_t)qrow * INNER + col] = f2bf(o[dd][r] * inv[r]);
        }
}

extern "C" void kernel_launch(void* const* d_in, const int* in_sizes, int n_in,
                              void* d_out, int out_size, void* d_ws, size_t ws_size,
                              hipStream_t stream) {
    const float* x    = (const float*)d_in[0];
    const float* y    = (const float*)d_in[1];
    const float* mask = (const float*)d_in[2];
    const float* Wq   = (const float*)d_in[3];
    const float* Wk   = (const float*)d_in[4];
    const float* Wv   = (const float*)d_in[5];
    const float* Wo   = (const float*)d_in[6];
    float* out = (float*)d_out;

    const size_t NX = (size_t)BATCH * LQ * DIM;    // 4.19M
    const size_t NS = (size_t)BATCH * LQ * INNER;  // 2.10M
    const size_t NW = (size_t)INNER * DIM;         // 0.52M
    unsigned short* xb  = (unsigned short*)d_ws;
    unsigned short* yb  = xb + NX;
    unsigned short* qb  = yb + NX;
    unsigned short* kb  = qb + NS;
    unsigned short* vt  = kb + NS;
    unsigned short* wqb = vt + NS;
    unsigned short* wkb = wqb + NW;
    unsigned short* wvb = wkb + NW;
    unsigned short* wob = wvb + NW;
    unsigned long long* mbits = (unsigned long long*)(wob + NW);
    unsigned short* ao  = xb;   // xb dead after proj
    // ws: 33.8 MB bf16 + 1 MB bits

    dim3 blk(256);
    prep<<<dim3(1024, 7), blk, 0, stream>>>(
        x, y, Wq, Wk, Wv, Wo, mask, xb, yb, wqb, wkb, wvb, wob, mbits);
    proj_qkv<<<dim3(4096 / 128, INNER / 64, 3), blk, 0, stream>>>(
        xb, yb, wqb, wkb, wvb, qb, kb, vt);
    attn_mfma<<<dim3(LQ / 64, HEADS, BATCH), blk, 0, stream>>>(
        qb, kb, vt, mbits, ao);
    gemm_out<<<dim3(4096 / 128, DIM / 64), blk, 0, stream>>>(ao, wob, out);
}